// Round 1
// baseline (560.436 us; speedup 1.0000x reference)
//
#include <hip/hip_runtime.h>
#include <hip/hip_bf16.h>

#define B_    8
#define O_    4
#define L_    1024
#define E_    1024
#define BETA_ 512
#define NSEG_ 12
#define BO_   32

// ws layout (float offsets)
#define WS_S    0
#define WS_X    (WS_S + BO_ * 12 * E_)
#define WS_E    (WS_X + BO_ * 13 * E_)
#define WS_T    (WS_E + BO_ * 13 * E_)
#define WS_IAB  (WS_T + BO_ * 10 * BETA_)
#define WS_CAT  (WS_IAB + BO_ * 2 * BETA_)

__device__ __forceinline__ float vget(const float4& v, int kk) {
    return (kk == 0) ? v.x : (kk == 1) ? v.y : (kk == 2) ? v.z : v.w;
}

// ---------------- K1: segment sums over L (the only big-memory kernel) ----------------
__global__ void k1_segsum(const float* __restrict__ hidden, const int* __restrict__ idx,
                          float* __restrict__ S) {
    const int bo = blockIdx.y;
    const int b = bo >> 2;  // bo = b*O_ + o
    int cuts[13];
    cuts[0] = 1;
#pragma unroll
    for (int i = 0; i < 12; ++i) cuts[i + 1] = idx[b * NSEG_ + i];
    const int rows = L_ / 32;
    const int l0 = blockIdx.x * rows;
    const int l1 = l0 + rows;
    int lo = l0 < 1 ? 1 : l0;
    const int hi = l1 < cuts[12] ? l1 : cuts[12];
    if (lo >= hi) return;
    const int e4 = threadIdx.x << 2;
    const float* base = hidden + (size_t)bo * (L_ * E_) + e4;
    int j = 0;
    while (j < 11 && cuts[j + 1] <= lo) ++j;
    int l = lo;
    while (l < hi) {
        const int e2 = (j < 11 && cuts[j + 1] < hi) ? cuts[j + 1] : hi;
        float sx = 0.f, sy = 0.f, sz = 0.f, sw = 0.f;
        for (; l < e2; ++l) {
            const float4 v = *reinterpret_cast<const float4*>(base + (size_t)l * E_);
            sx += v.x; sy += v.y; sz += v.z; sw += v.w;
        }
        float* sp = S + ((size_t)bo * 12 + j) * E_ + e4;
        atomicAdd(sp + 0, sx);
        atomicAdd(sp + 1, sy);
        atomicAdd(sp + 2, sz);
        atomicAdd(sp + 3, sw);
        ++j;
    }
}

// ---------------- K2: X rows = segment means (rows 0..9 ctx, 10 q, 11 o, 12 allc) -----
__global__ void k2_means(const float* __restrict__ S, const int* __restrict__ idx,
                         float* __restrict__ X) {
    const int bo = blockIdx.x;
    const int b = bo >> 2;
    int cuts[13];
    cuts[0] = 1;
#pragma unroll
    for (int i = 0; i < 12; ++i) cuts[i + 1] = idx[b * NSEG_ + i];
    const int e4 = threadIdx.x << 2;
    const float4* Sp = reinterpret_cast<const float4*>(S + (size_t)bo * 12 * E_ + e4);
    float4* Xp = reinterpret_cast<float4*>(X + (size_t)bo * 13 * E_ + e4);
    float ax = 0.f, ay = 0.f, az = 0.f, aw = 0.f;
#pragma unroll
    for (int r = 0; r < 12; ++r) {
        const float4 s = Sp[r * (E_ / 4)];
        const float inv = 1.0f / (float)(cuts[r + 1] - cuts[r]);
        float4 m;
        m.x = s.x * inv; m.y = s.y * inv; m.z = s.z * inv; m.w = s.w * inv;
        Xp[r * (E_ / 4)] = m;
        if (r < 10) { ax += s.x; ay += s.y; az += s.z; aw += s.w; }
    }
    const float inva = 1.0f / (float)(cuts[10] - 1);
    float4 m;
    m.x = ax * inva; m.y = ay * inva; m.z = az * inva; m.w = aw * inva;
    Xp[12 * (E_ / 4)] = m;
}

// ---------------- K3: E = 1 + relu(X @ Wp + bp), rows 0..12, cols 0..1023 -------------
__global__ void k3_param(const float* __restrict__ X, const float* __restrict__ Wp,
                         const float* __restrict__ bp, float* __restrict__ Eb) {
    const int bo = blockIdx.y;
    const int c = blockIdx.x * 256 + threadIdx.x;
    const float4* __restrict__ Xp = reinterpret_cast<const float4*>(X + (size_t)bo * 13 * E_);
    float acc[13];
#pragma unroll
    for (int r = 0; r < 13; ++r) acc[r] = 0.f;
    for (int k4 = 0; k4 < E_ / 4; ++k4) {
        float4 xv[13];
#pragma unroll
        for (int r = 0; r < 13; ++r) xv[r] = Xp[r * (E_ / 4) + k4];
#pragma unroll
        for (int kk = 0; kk < 4; ++kk) {
            const float w = Wp[(size_t)(k4 * 4 + kk) * (2 * BETA_) + c];
#pragma unroll
            for (int r = 0; r < 13; ++r) acc[r] = fmaf(vget(xv[r], kk), w, acc[r]);
        }
    }
    const float bc = bp[c];
#pragma unroll
    for (int r = 0; r < 13; ++r) {
        float v = acc[r] + bc;
        v = v > 0.f ? v : 0.f;
        Eb[((size_t)bo * 13 + r) * E_ + c] = 1.f + v;
    }
}

// ---------------- K4: attention pool 1 (h, logits t, softmax over j, ia/ib) -----------
__global__ void __launch_bounds__(512) k4_attn1(
    const float* __restrict__ Eb, const float* __restrict__ Wa0,
    const float* __restrict__ ba0, const float* __restrict__ Wa,
    const float* __restrict__ ba, float* __restrict__ T, float* __restrict__ IAB) {
    const int bo = blockIdx.x;
    const int c = threadIdx.x;  // 0..511
    __shared__ float h_lds[10][BETA_];
    const float* __restrict__ Ep = Eb + (size_t)bo * 13 * E_;
    const float4* __restrict__ Ep4 = reinterpret_cast<const float4*>(Ep);
    float acc[10];
#pragma unroll
    for (int j = 0; j < 10; ++j) acc[j] = 0.f;
    for (int k4 = 0; k4 < E_ / 4; ++k4) {
        float4 ev[10];
#pragma unroll
        for (int j = 0; j < 10; ++j) ev[j] = Ep4[j * (E_ / 4) + k4];
#pragma unroll
        for (int kk = 0; kk < 4; ++kk) {
            const float w = Wa0[(size_t)(k4 * 4 + kk) * BETA_ + c];
#pragma unroll
            for (int j = 0; j < 10; ++j) acc[j] = fmaf(vget(ev[j], kk), w, acc[j]);
        }
    }
    const float b0 = ba0[c];
#pragma unroll
    for (int j = 0; j < 10; ++j) {
        const float h = acc[j] + b0;
        h_lds[j][c] = h > 0.f ? h : 0.f;
    }
    __syncthreads();
    float t[10];
#pragma unroll
    for (int j = 0; j < 10; ++j) t[j] = 0.f;
    for (int k4 = 0; k4 < BETA_ / 4; ++k4) {
        float4 hv[10];
#pragma unroll
        for (int j = 0; j < 10; ++j) hv[j] = *reinterpret_cast<const float4*>(&h_lds[j][k4 * 4]);
#pragma unroll
        for (int kk = 0; kk < 4; ++kk) {
            const float w = Wa[(size_t)(k4 * 4 + kk) * BETA_ + c];
#pragma unroll
            for (int j = 0; j < 10; ++j) t[j] = fmaf(vget(hv[j], kk), w, t[j]);
        }
    }
    const float bac = ba[c];
#pragma unroll
    for (int j = 0; j < 10; ++j) {
        t[j] += bac;
        T[((size_t)bo * 10 + j) * BETA_ + c] = t[j];  // pre-softmax logits for pool 2
    }
    float m = t[0];
#pragma unroll
    for (int j = 1; j < 10; ++j) m = fmaxf(m, t[j]);
    float p[10];
    float sw = 0.f;
#pragma unroll
    for (int j = 0; j < 10; ++j) { p[j] = expf(t[j] - m); sw += p[j]; }
    const float invsw = 1.0f / sw;
    float ia = 0.f, ib = 0.f;
#pragma unroll
    for (int j = 0; j < 10; ++j) {
        const float pj = p[j] * invsw;
        ia = fmaf(pj, Ep[(size_t)j * E_ + c], ia);
        ib = fmaf(pj, Ep[(size_t)j * E_ + BETA_ + c], ib);
    }
    IAB[(size_t)bo * 1024 + c] = ia;
    IAB[(size_t)bo * 1024 + BETA_ + c] = ib;
}

// ---------------- K5: pools 2+3 fused, builds cat -------------------------------------
__global__ void __launch_bounds__(512) k5_attn23(
    const float* __restrict__ Eb, const float* __restrict__ Wa0,
    const float* __restrict__ ba0, const float* __restrict__ Wa,
    const float* __restrict__ ba, const float* __restrict__ T,
    const float* __restrict__ IAB, float* __restrict__ CAT) {
    const int bo = blockIdx.x;
    const int c = threadIdx.x;  // 0..511
    __shared__ float hI_lds[BETA_];
    __shared__ float rn_lds[10][E_];
    __shared__ float h3_lds[10][BETA_];
    const float* __restrict__ Ep = Eb + (size_t)bo * 13 * E_;
    const float* __restrict__ iab = IAB + (size_t)bo * 1024;
    const float4* __restrict__ iab4 = reinterpret_cast<const float4*>(iab);
    // phase 1: hI = relu([ia,ib] @ Wa0 + ba0)  (the shared s=1 row of pool 2)
    float a1 = 0.f;
    for (int k4 = 0; k4 < E_ / 4; ++k4) {
        const float4 iv = iab4[k4];
#pragma unroll
        for (int kk = 0; kk < 4; ++kk)
            a1 = fmaf(vget(iv, kk), Wa0[(size_t)(k4 * 4 + kk) * BETA_ + c], a1);
    }
    a1 += ba0[c];
    hI_lds[c] = a1 > 0.f ? a1 : 0.f;
    __syncthreads();
    // phase 2: tI = hI @ Wa + ba
    float tI = 0.f;
    for (int k4 = 0; k4 < BETA_ / 4; ++k4) {
        const float4 hv = *reinterpret_cast<const float4*>(&hI_lds[k4 * 4]);
#pragma unroll
        for (int kk = 0; kk < 4; ++kk)
            tI = fmaf(vget(hv, kk), Wa[(size_t)(k4 * 4 + kk) * BETA_ + c], tI);
    }
    tI += ba[c];
    // phase 3: na/nb via 2-way softmax(t[j], tI); rn = 1/na, 1/nb
    const float ia = iab[c];
    const float ib2 = iab[BETA_ + c];
    float rna[10], rnb[10];
#pragma unroll
    for (int j = 0; j < 10; ++j) {
        const float tj = T[((size_t)bo * 10 + j) * BETA_ + c];
        const float aj = Ep[(size_t)j * E_ + c];
        const float bj = Ep[(size_t)j * E_ + BETA_ + c];
        const float m = fmaxf(tj, tI);
        const float e0 = expf(tj - m);
        const float e1 = expf(tI - m);
        const float inv = 1.0f / (e0 + e1);
        const float na = (e0 * aj + e1 * ia) * inv;
        const float nb = (e0 * bj + e1 * ib2) * inv;
        rna[j] = 1.0f / na;
        rnb[j] = 1.0f / nb;
        rn_lds[j][c] = rna[j];
        rn_lds[j][BETA_ + c] = rnb[j];
    }
    __syncthreads();
    // phase 4: h3 = relu([1/na, 1/nb] @ Wa0 + ba0)
    float acc3[10];
#pragma unroll
    for (int j = 0; j < 10; ++j) acc3[j] = 0.f;
    for (int k4 = 0; k4 < E_ / 4; ++k4) {
        float4 rv[10];
#pragma unroll
        for (int j = 0; j < 10; ++j) rv[j] = *reinterpret_cast<const float4*>(&rn_lds[j][k4 * 4]);
#pragma unroll
        for (int kk = 0; kk < 4; ++kk) {
            const float w = Wa0[(size_t)(k4 * 4 + kk) * BETA_ + c];
#pragma unroll
            for (int j = 0; j < 10; ++j) acc3[j] = fmaf(vget(rv[j], kk), w, acc3[j]);
        }
    }
    const float b0 = ba0[c];
#pragma unroll
    for (int j = 0; j < 10; ++j) {
        const float h = acc3[j] + b0;
        h3_lds[j][c] = h > 0.f ? h : 0.f;
    }
    __syncthreads();
    // phase 5: t3 = h3 @ Wa + ba, softmax over j, ua/ub
    float t3[10];
#pragma unroll
    for (int j = 0; j < 10; ++j) t3[j] = 0.f;
    for (int k4 = 0; k4 < BETA_ / 4; ++k4) {
        float4 hv[10];
#pragma unroll
        for (int j = 0; j < 10; ++j) hv[j] = *reinterpret_cast<const float4*>(&h3_lds[j][k4 * 4]);
#pragma unroll
        for (int kk = 0; kk < 4; ++kk) {
            const float w = Wa[(size_t)(k4 * 4 + kk) * BETA_ + c];
#pragma unroll
            for (int j = 0; j < 10; ++j) t3[j] = fmaf(vget(hv[j], kk), w, t3[j]);
        }
    }
    const float bac = ba[c];
    float m3 = -1e30f;
#pragma unroll
    for (int j = 0; j < 10; ++j) { t3[j] += bac; m3 = fmaxf(m3, t3[j]); }
    float p3[10];
    float sw3 = 0.f;
#pragma unroll
    for (int j = 0; j < 10; ++j) { p3[j] = expf(t3[j] - m3); sw3 += p3[j]; }
    const float inv3 = 1.0f / sw3;
    float uap = 0.f, ubp = 0.f;
#pragma unroll
    for (int j = 0; j < 10; ++j) {
        uap = fmaf(p3[j], rna[j], uap);
        ubp = fmaf(p3[j], rnb[j], ubp);
    }
    const float ua = sw3 / uap * inv3 * sw3;  // placeholder avoided below; compute directly:
    float* catp = CAT + (size_t)bo * 4096;
    catp[c] = 1.0f / (uap * inv3);
    catp[BETA_ + c] = 1.0f / (ubp * inv3);
    // cat tail: [a_ac|b_ac] = E row 12, [a_o|b_o] = row 11, [a_q|b_q] = row 10
    catp[1024 + c] = Ep[12 * E_ + c];
    catp[1024 + BETA_ + c] = Ep[12 * E_ + BETA_ + c];
    catp[2048 + c] = Ep[11 * E_ + c];
    catp[2048 + BETA_ + c] = Ep[11 * E_ + BETA_ + c];
    catp[3072 + c] = Ep[10 * E_ + c];
    catp[3072 + BETA_ + c] = Ep[10 * E_ + BETA_ + c];
    (void)ua;
}

// ---------------- K6: out = relu(cat @ Wl0 + bl0) @ Wl + bl ---------------------------
__global__ void __launch_bounds__(512) k6_final(
    const float* __restrict__ CAT, const float* __restrict__ Wl0,
    const float* __restrict__ bl0, const float* __restrict__ Wl,
    const float* __restrict__ bl, float* __restrict__ out) {
    const int bo = blockIdx.x;
    const int c = threadIdx.x;  // 0..511
    const float4* __restrict__ cp4 = reinterpret_cast<const float4*>(CAT + (size_t)bo * 4096);
    float acc = 0.f;
    for (int k4 = 0; k4 < 4096 / 4; ++k4) {
        const float4 cv = cp4[k4];
        const float* wrow = Wl0 + (size_t)(k4 * 4) * BETA_ + c;
        acc = fmaf(cv.x, wrow[0], acc);
        acc = fmaf(cv.y, wrow[BETA_], acc);
        acc = fmaf(cv.z, wrow[2 * BETA_], acc);
        acc = fmaf(cv.w, wrow[3 * BETA_], acc);
    }
    acc += bl0[c];
    acc = acc > 0.f ? acc : 0.f;
    float partial = acc * Wl[c];
#pragma unroll
    for (int off = 32; off > 0; off >>= 1) partial += __shfl_down(partial, off, 64);
    __shared__ float red[8];
    if ((c & 63) == 0) red[c >> 6] = partial;
    __syncthreads();
    if (c == 0) {
        float s = 0.f;
#pragma unroll
        for (int i = 0; i < 8; ++i) s += red[i];
        out[bo] = s + bl[0];
    }
}

extern "C" void kernel_launch(void* const* d_in, const int* in_sizes, int n_in,
                              void* d_out, int out_size, void* d_ws, size_t ws_size,
                              hipStream_t stream) {
    const float* hidden = (const float*)d_in[0];
    const int* idx = (const int*)d_in[1];
    const float* Wp  = (const float*)d_in[2];
    const float* bp  = (const float*)d_in[3];
    const float* Wa0 = (const float*)d_in[4];
    const float* ba0 = (const float*)d_in[5];
    const float* Wa  = (const float*)d_in[6];
    const float* ba  = (const float*)d_in[7];
    const float* Wl0 = (const float*)d_in[8];
    const float* bl0 = (const float*)d_in[9];
    const float* Wl  = (const float*)d_in[10];
    const float* bl  = (const float*)d_in[11];
    float* ws = (float*)d_ws;
    float* S   = ws + WS_S;
    float* X   = ws + WS_X;
    float* Eb  = ws + WS_E;
    float* T   = ws + WS_T;
    float* IAB = ws + WS_IAB;
    float* CAT = ws + WS_CAT;

    hipMemsetAsync(S, 0, (size_t)BO_ * 12 * E_ * sizeof(float), stream);
    k1_segsum<<<dim3(32, BO_), 256, 0, stream>>>(hidden, idx, S);
    k2_means<<<BO_, 256, 0, stream>>>(S, idx, X);
    k3_param<<<dim3(4, BO_), 256, 0, stream>>>(X, Wp, bp, Eb);
    k4_attn1<<<BO_, 512, 0, stream>>>(Eb, Wa0, ba0, Wa, ba, T, IAB);
    k5_attn23<<<BO_, 512, 0, stream>>>(Eb, Wa0, ba0, Wa, ba, T, IAB, CAT);
    k6_final<<<BO_, 512, 0, stream>>>(CAT, Wl0, bl0, Wl, bl, (float*)d_out);
}

// Round 2
// 193.072 us; speedup vs baseline: 2.9027x; 2.9027x over previous
//
#include <hip/hip_runtime.h>
#include <hip/hip_bf16.h>

#define B_    8
#define O_    4
#define L_    1024
#define E_    1024
#define BETA_ 512
#define NSEG_ 12
#define BO_   32

// ---- workspace layout (float offsets). [WS_S .. WS_ACC_END) is memset to 0 each call.
enum : size_t {
  WS_S       = 0,
  WS_P1      = WS_S   + (size_t)BO_ * 12 * E_,     // raw X@Wp acc (32x13x1024)
  WS_H1      = WS_P1  + (size_t)BO_ * 13 * E_,     // raw tE@Wa0   (32x10x512)
  WS_T1      = WS_H1  + (size_t)BO_ * 10 * BETA_,  // raw h@Wa     (32x10x512)
  WS_H2      = WS_T1  + (size_t)BO_ * 10 * BETA_,  // raw IAB@Wa0  (32x512)
  WS_T2      = WS_H2  + (size_t)BO_ * BETA_,       // raw hI@Wa    (32x512)
  WS_H3      = WS_T2  + (size_t)BO_ * BETA_,       // raw RN@Wa0   (32x10x512)
  WS_T3      = WS_H3  + (size_t)BO_ * 10 * BETA_,  // raw h3@Wa    (32x10x512)
  WS_HF      = WS_T3  + (size_t)BO_ * 10 * BETA_,  // raw CAT@Wl0  (32x512)
  WS_ACC_END = WS_HF  + (size_t)BO_ * BETA_,
  WS_X       = WS_ACC_END,                          // seg means   (32x13x1024)
  WS_IAB     = WS_X   + (size_t)BO_ * 13 * E_,     // ia|ib       (32x1024)
  WS_RN      = WS_IAB + (size_t)BO_ * 2 * BETA_,   // 1/na|1/nb   (32x10x1024)
  WS_CAT     = WS_RN  + (size_t)BO_ * 10 * E_,     // cat         (32x4096)
  WS_END     = WS_CAT + (size_t)BO_ * 8 * BETA_,
};

__device__ __forceinline__ float relu_(float v) { return v > 0.f ? v : 0.f; }

// ---------------- K1: segment sums over L (the only big-memory kernel) ----------------
__global__ void k1_segsum(const float* __restrict__ hidden, const int* __restrict__ idx,
                          float* __restrict__ S) {
    const int bo = blockIdx.y;
    const int b = bo >> 2;
    int cuts[13];
    cuts[0] = 1;
#pragma unroll
    for (int i = 0; i < 12; ++i) cuts[i + 1] = idx[b * NSEG_ + i];
    const int rows = L_ / 64;
    const int l0 = blockIdx.x * rows;
    const int l1 = l0 + rows;
    int lo = l0 < 1 ? 1 : l0;
    const int hi = l1 < cuts[12] ? l1 : cuts[12];
    if (lo >= hi) return;
    const int e4 = threadIdx.x << 2;
    const float* base = hidden + (size_t)bo * (L_ * E_) + e4;
    int j = 0;
    while (j < 11 && cuts[j + 1] <= lo) ++j;
    int l = lo;
    while (l < hi) {
        const int e2 = (j < 11 && cuts[j + 1] < hi) ? cuts[j + 1] : hi;
        float sx = 0.f, sy = 0.f, sz = 0.f, sw = 0.f;
        for (; l < e2; ++l) {
            const float4 v = *reinterpret_cast<const float4*>(base + (size_t)l * E_);
            sx += v.x; sy += v.y; sz += v.z; sw += v.w;
        }
        float* sp = S + ((size_t)bo * 12 + j) * E_ + e4;
        atomicAdd(sp + 0, sx);
        atomicAdd(sp + 1, sy);
        atomicAdd(sp + 2, sz);
        atomicAdd(sp + 3, sw);
        ++j;
    }
}

// ---------------- K2: X rows = segment means (rows 0..9 ctx, 10 q, 11 o, 12 allc) -----
__global__ void k2_means(const float* __restrict__ S, const int* __restrict__ idx,
                         float* __restrict__ X) {
    const int bo = blockIdx.x;
    const int b = bo >> 2;
    int cuts[13];
    cuts[0] = 1;
#pragma unroll
    for (int i = 0; i < 12; ++i) cuts[i + 1] = idx[b * NSEG_ + i];
    const int e4 = threadIdx.x << 2;
    const float4* Sp = reinterpret_cast<const float4*>(S + (size_t)bo * 12 * E_ + e4);
    float4* Xp = reinterpret_cast<float4*>(X + (size_t)bo * 13 * E_ + e4);
    float ax = 0.f, ay = 0.f, az = 0.f, aw = 0.f;
#pragma unroll
    for (int r = 0; r < 12; ++r) {
        const float4 s = Sp[r * (E_ / 4)];
        const float inv = 1.0f / (float)(cuts[r + 1] - cuts[r]);
        float4 m;
        m.x = s.x * inv; m.y = s.y * inv; m.z = s.z * inv; m.w = s.w * inv;
        Xp[r * (E_ / 4)] = m;
        if (r < 10) { ax += s.x; ay += s.y; az += s.z; aw += s.w; }
    }
    const float inva = 1.0f / (float)(cuts[10] - 1);
    float4 m;
    m.x = ax * inva; m.y = ay * inva; m.z = az * inva; m.w = aw * inva;
    Xp[12 * (E_ / 4)] = m;
}

// ---------------- split-K / split-bo / split-N GEMM with fused x-load transform -------
// OUT[(bo*M + m)*N + c] += sum_k xform(X[bo*XBO + m*K + k]) * W[k*N + c]
// XF: 0 = identity, 1 = 1+relu(v+bias[k]), 2 = relu(v+bias[k])
template<int M, int K, int N, int KC, int BOG, int XF, int XBO>
__global__ __launch_bounds__(256) void gemm_sk(
    const float* __restrict__ Xb, const float* __restrict__ xbias,
    const float* __restrict__ W, float* __restrict__ OUT) {
    const int k0  = blockIdx.x * KC;
    const int bo0 = blockIdx.y * BOG;
    const int c   = blockIdx.z * 256 + threadIdx.x;
    __shared__ __align__(16) float xs[BOG * M * KC];
    for (int i = threadIdx.x; i < BOG * M * KC; i += 256) {
        const int kk = i % KC;
        const int rm = i / KC;
        const int m  = rm % M;
        const int b  = rm / M;
        float v = Xb[(size_t)(bo0 + b) * XBO + (size_t)m * K + k0 + kk];
        if constexpr (XF >= 1) {
            v += xbias[k0 + kk];
            v = relu_(v);
            if constexpr (XF == 1) v += 1.f;
        }
        xs[i] = v;
    }
    __syncthreads();
    float acc[BOG][M];
#pragma unroll
    for (int b = 0; b < BOG; ++b)
#pragma unroll
        for (int m = 0; m < M; ++m) acc[b][m] = 0.f;
    const float* __restrict__ wp = W + (size_t)k0 * N + c;
    for (int k4 = 0; k4 < KC / 4; ++k4) {
        const float w0 = wp[(size_t)(4 * k4 + 0) * N];
        const float w1 = wp[(size_t)(4 * k4 + 1) * N];
        const float w2 = wp[(size_t)(4 * k4 + 2) * N];
        const float w3 = wp[(size_t)(4 * k4 + 3) * N];
#pragma unroll
        for (int b = 0; b < BOG; ++b) {
#pragma unroll
            for (int m = 0; m < M; ++m) {
                const float4 xv = *reinterpret_cast<const float4*>(&xs[(b * M + m) * KC + 4 * k4]);
                float a = acc[b][m];
                a = fmaf(xv.x, w0, a);
                a = fmaf(xv.y, w1, a);
                a = fmaf(xv.z, w2, a);
                a = fmaf(xv.w, w3, a);
                acc[b][m] = a;
            }
        }
    }
#pragma unroll
    for (int b = 0; b < BOG; ++b) {
        float* op = OUT + (size_t)(bo0 + b) * M * N + c;
#pragma unroll
        for (int m = 0; m < M; ++m) atomicAdd(op + (size_t)m * N, acc[b][m]);
    }
}

// ---------------- ep3: pool-1 softmax over j -> IAB (ia|ib) --------------------------
__global__ void __launch_bounds__(512) ep3_iab(
    const float* __restrict__ P1, const float* __restrict__ bp,
    const float* __restrict__ T1, const float* __restrict__ ba,
    float* __restrict__ IAB) {
    const int bo = blockIdx.x;
    const int c = threadIdx.x;
    const float bac = ba[c];
    float t[10];
#pragma unroll
    for (int j = 0; j < 10; ++j) t[j] = T1[((size_t)bo * 10 + j) * BETA_ + c] + bac;
    float m = t[0];
#pragma unroll
    for (int j = 1; j < 10; ++j) m = fmaxf(m, t[j]);
    float p[10], sw = 0.f;
#pragma unroll
    for (int j = 0; j < 10; ++j) { p[j] = expf(t[j] - m); sw += p[j]; }
    const float inv = 1.0f / sw;
    const float bpa = bp[c], bpb = bp[BETA_ + c];
    const float* Pp = P1 + (size_t)bo * 13 * E_;
    float ia = 0.f, ib = 0.f;
#pragma unroll
    for (int j = 0; j < 10; ++j) {
        const float pj = p[j] * inv;
        const float ea = 1.f + relu_(Pp[(size_t)j * E_ + c] + bpa);
        const float eb = 1.f + relu_(Pp[(size_t)j * E_ + BETA_ + c] + bpb);
        ia = fmaf(pj, ea, ia);
        ib = fmaf(pj, eb, ib);
    }
    IAB[(size_t)bo * 1024 + c] = ia;
    IAB[(size_t)bo * 1024 + BETA_ + c] = ib;
}

// ---------------- ep5: pool-2 (2-way softmax t[j] vs tI) -> RN = 1/na | 1/nb ----------
__global__ void __launch_bounds__(512) ep5_rn(
    const float* __restrict__ P1, const float* __restrict__ bp,
    const float* __restrict__ T1, const float* __restrict__ T2,
    const float* __restrict__ ba, const float* __restrict__ IAB,
    float* __restrict__ RN) {
    const int bo = blockIdx.x;
    const int c = threadIdx.x;
    const float bac = ba[c];
    const float tI = T2[(size_t)bo * BETA_ + c] + bac;
    const float ia = IAB[(size_t)bo * 1024 + c];
    const float ib = IAB[(size_t)bo * 1024 + BETA_ + c];
    const float bpa = bp[c], bpb = bp[BETA_ + c];
    const float* Pp = P1 + (size_t)bo * 13 * E_;
#pragma unroll
    for (int j = 0; j < 10; ++j) {
        const float tj = T1[((size_t)bo * 10 + j) * BETA_ + c] + bac;
        const float m = fmaxf(tj, tI);
        const float e0 = expf(tj - m);
        const float e1 = expf(tI - m);
        const float inv = 1.0f / (e0 + e1);
        const float ea = 1.f + relu_(Pp[(size_t)j * E_ + c] + bpa);
        const float eb = 1.f + relu_(Pp[(size_t)j * E_ + BETA_ + c] + bpb);
        const float na = (e0 * ea + e1 * ia) * inv;
        const float nb = (e0 * eb + e1 * ib) * inv;
        RN[((size_t)bo * 10 + j) * E_ + c] = 1.0f / na;
        RN[((size_t)bo * 10 + j) * E_ + BETA_ + c] = 1.0f / nb;
    }
}

// ---------------- ep7: pool-3 softmax over j -> ua/ub, build CAT ----------------------
__global__ void __launch_bounds__(512) ep7_cat(
    const float* __restrict__ P1, const float* __restrict__ bp,
    const float* __restrict__ T3, const float* __restrict__ ba,
    const float* __restrict__ RN, float* __restrict__ CAT) {
    const int bo = blockIdx.x;
    const int c = threadIdx.x;
    const float bac = ba[c];
    float t[10];
#pragma unroll
    for (int j = 0; j < 10; ++j) t[j] = T3[((size_t)bo * 10 + j) * BETA_ + c] + bac;
    float m = t[0];
#pragma unroll
    for (int j = 1; j < 10; ++j) m = fmaxf(m, t[j]);
    float p[10], sw = 0.f;
#pragma unroll
    for (int j = 0; j < 10; ++j) { p[j] = expf(t[j] - m); sw += p[j]; }
    const float inv = 1.0f / sw;
    float uap = 0.f, ubp = 0.f;
#pragma unroll
    for (int j = 0; j < 10; ++j) {
        const float pj = p[j] * inv;
        uap = fmaf(pj, RN[((size_t)bo * 10 + j) * E_ + c], uap);
        ubp = fmaf(pj, RN[((size_t)bo * 10 + j) * E_ + BETA_ + c], ubp);
    }
    const float bpa = bp[c], bpb = bp[BETA_ + c];
    const float* Pp = P1 + (size_t)bo * 13 * E_;
    float* catp = CAT + (size_t)bo * 4096;
    catp[c] = 1.0f / uap;
    catp[BETA_ + c] = 1.0f / ubp;
    catp[1024 + c]          = 1.f + relu_(Pp[12 * E_ + c] + bpa);
    catp[1024 + BETA_ + c]  = 1.f + relu_(Pp[12 * E_ + BETA_ + c] + bpb);
    catp[2048 + c]          = 1.f + relu_(Pp[11 * E_ + c] + bpa);
    catp[2048 + BETA_ + c]  = 1.f + relu_(Pp[11 * E_ + BETA_ + c] + bpb);
    catp[3072 + c]          = 1.f + relu_(Pp[10 * E_ + c] + bpa);
    catp[3072 + BETA_ + c]  = 1.f + relu_(Pp[10 * E_ + BETA_ + c] + bpb);
}

// ---------------- final: out[bo] = relu(HF+bl0) . Wl + bl -----------------------------
__global__ void __launch_bounds__(512) k_final(
    const float* __restrict__ HF, const float* __restrict__ bl0,
    const float* __restrict__ Wl, const float* __restrict__ bl,
    float* __restrict__ out) {
    const int bo = blockIdx.x;
    const int c = threadIdx.x;
    float v = relu_(HF[(size_t)bo * BETA_ + c] + bl0[c]);
    float partial = v * Wl[c];
#pragma unroll
    for (int off = 32; off > 0; off >>= 1) partial += __shfl_down(partial, off, 64);
    __shared__ float red[8];
    if ((c & 63) == 0) red[c >> 6] = partial;
    __syncthreads();
    if (c == 0) {
        float s = 0.f;
#pragma unroll
        for (int i = 0; i < 8; ++i) s += red[i];
        out[bo] = s + bl[0];
    }
}

extern "C" void kernel_launch(void* const* d_in, const int* in_sizes, int n_in,
                              void* d_out, int out_size, void* d_ws, size_t ws_size,
                              hipStream_t stream) {
    const float* hidden = (const float*)d_in[0];
    const int* idx = (const int*)d_in[1];
    const float* Wp  = (const float*)d_in[2];
    const float* bp  = (const float*)d_in[3];
    const float* Wa0 = (const float*)d_in[4];
    const float* ba0 = (const float*)d_in[5];
    const float* Wa  = (const float*)d_in[6];
    const float* ba  = (const float*)d_in[7];
    const float* Wl0 = (const float*)d_in[8];
    const float* bl0 = (const float*)d_in[9];
    const float* Wl  = (const float*)d_in[10];
    const float* bl  = (const float*)d_in[11];
    float* ws = (float*)d_ws;
    float* S   = ws + WS_S;
    float* P1  = ws + WS_P1;
    float* H1  = ws + WS_H1;
    float* T1  = ws + WS_T1;
    float* H2  = ws + WS_H2;
    float* T2  = ws + WS_T2;
    float* H3  = ws + WS_H3;
    float* T3  = ws + WS_T3;
    float* HF  = ws + WS_HF;
    float* X   = ws + WS_X;
    float* IAB = ws + WS_IAB;
    float* RN  = ws + WS_RN;
    float* CAT = ws + WS_CAT;

    hipMemsetAsync(S, 0, (size_t)(WS_ACC_END - WS_S) * sizeof(float), stream);
    k1_segsum<<<dim3(64, BO_), 256, 0, stream>>>(hidden, idx, S);
    k2_means<<<BO_, 256, 0, stream>>>(S, idx, X);
    // G1: P1 = X @ Wp   (M=13, K=1024, N=1024)
    gemm_sk<13, 1024, 1024, 128, 2, 0, 13 * 1024>
        <<<dim3(8, 16, 4), 256, 0, stream>>>(X, nullptr, Wp, P1);
    // G2: H1 = tE(rows 0..9) @ Wa0
    gemm_sk<10, 1024, 512, 64, 2, 1, 13 * 1024>
        <<<dim3(16, 16, 2), 256, 0, stream>>>(P1, bp, Wa0, H1);
    // G3: T1 = relu(H1+ba0) @ Wa
    gemm_sk<10, 512, 512, 64, 2, 2, 10 * 512>
        <<<dim3(8, 16, 2), 256, 0, stream>>>(H1, ba0, Wa, T1);
    ep3_iab<<<BO_, 512, 0, stream>>>(P1, bp, T1, ba, IAB);
    // G4: H2 = IAB @ Wa0
    gemm_sk<1, 1024, 512, 128, 8, 0, 1024>
        <<<dim3(8, 4, 2), 256, 0, stream>>>(IAB, nullptr, Wa0, H2);
    // G5: T2 = relu(H2+ba0) @ Wa
    gemm_sk<1, 512, 512, 64, 8, 2, 512>
        <<<dim3(8, 4, 2), 256, 0, stream>>>(H2, ba0, Wa, T2);
    ep5_rn<<<BO_, 512, 0, stream>>>(P1, bp, T1, T2, ba, IAB, RN);
    // G6: H3 = RN @ Wa0
    gemm_sk<10, 1024, 512, 64, 2, 0, 10 * 1024>
        <<<dim3(16, 16, 2), 256, 0, stream>>>(RN, nullptr, Wa0, H3);
    // G7: T3 = relu(H3+ba0) @ Wa
    gemm_sk<10, 512, 512, 64, 2, 2, 10 * 512>
        <<<dim3(8, 16, 2), 256, 0, stream>>>(H3, ba0, Wa, T3);
    ep7_cat<<<BO_, 512, 0, stream>>>(P1, bp, T3, ba, RN, CAT);
    // G8: HF = CAT @ Wl0  (K=4096)
    gemm_sk<1, 4096, 512, 64, 8, 0, 4096>
        <<<dim3(64, 4, 2), 256, 0, stream>>>(CAT, nullptr, Wl0, HF);
    k_final<<<BO_, 512, 0, stream>>>(HF, bl0, Wl, bl, (float*)d_out);
}